// Round 1
// baseline (2397.681 us; speedup 1.0000x reference)
//
#include <hip/hip_runtime.h>
#include <hip/hip_bf16.h>

#define WAVE 64

__device__ __forceinline__ float siluf(float x) {
    return x / (1.0f + __expf(-x));
}

// ---------------- init: species + s = W_embed[z], v = 0 ----------------
__global__ void k_init(const float* __restrict__ attrs, const float* __restrict__ Wemb,
                       int* __restrict__ species, float* __restrict__ s,
                       float* __restrict__ v, int N) {
    int lane = threadIdx.x;
    int n0 = blockIdx.x * 64;
    for (int r = 0; r < 64; r++) {
        int n = n0 + r;
        if (n >= N) break;
        float a = (lane < 10) ? attrs[n * 10 + lane] : 0.0f;
        unsigned long long m = __ballot(a > 0.5f);
        int z = __ffsll(m) - 1;
        if (lane == 0) species[n] = z;
        s[n * 64 + lane] = Wemb[z * 64 + lane];
        v[n * 192 + lane] = 0.0f;
        v[n * 192 + 64 + lane] = 0.0f;
        v[n * 192 + 128 + lane] = 0.0f;
    }
}

// ---------------- geometry + radial basis (layer-invariant) ----------------
__global__ void k_geom(const int* __restrict__ ei, const float* __restrict__ pos,
                       const float* __restrict__ shifts, float* __restrict__ Y1v,
                       float* __restrict__ efT, int E) {
    int e = blockIdx.x * 64 + threadIdx.x;
    if (e >= E) return;
    int snd = ei[e], rcv = ei[E + e];
    float dx = pos[rcv * 3 + 0] - pos[snd * 3 + 0] + shifts[e * 3 + 0];
    float dy = pos[rcv * 3 + 1] - pos[snd * 3 + 1] + shifts[e * 3 + 1];
    float dz = pos[rcv * 3 + 2] - pos[snd * 3 + 2] + shifts[e * 3 + 2];
    float r = sqrtf(dx * dx + dy * dy + dz * dz);
    float rin = 1.0f / (r + 1e-9f);
    const float SQ3 = 1.7320508075688772f;
    Y1v[e * 3 + 0] = SQ3 * dx * rin;
    Y1v[e * 3 + 1] = SQ3 * dy * rin;
    Y1v[e * 3 + 2] = SQ3 * dz * rin;
    float u = r * 0.2f;  // r / R_MAX
    float env = 0.0f;
    if (u < 1.0f) {
        float u2 = u * u;
        float u6 = u2 * u2 * u2;
        env = 1.0f - 28.0f * u6 + 48.0f * u6 * u - 21.0f * u6 * u2;
    }
    const float PIF = 3.14159265358979f;
    float x = PIF * u;
    float sp = __sinf(x), cp = __cosf(x);
    float coef = 0.6324555320336759f * rin * env;  // sqrt(2/5) * env / (r+eps)
    // sin(n*pi*u) by Chebyshev recurrence
    float sm1 = 0.0f, scur = sp, twoc = 2.0f * cp;
    #pragma unroll
    for (int k = 0; k < 8; k++) {
        efT[k * (size_t)E + e] = coef * scur;
        float nxt = twoc * scur - sm1;
        sm1 = scur; scur = nxt;
    }
}

// ---------------- generic 64-node tile GEMV: out = in @ W (64x64) ----------------
__device__ __forceinline__ void tile_mv64(const float* __restrict__ in, int istride,
                                          const float* __restrict__ W,
                                          float* __restrict__ outp, int ostride,
                                          int n0, int nv, float* lds, int lane) {
    for (int r = 0; r < nv; r++) lds[r * 65 + lane] = in[(size_t)(n0 + r) * istride + lane];
    __syncthreads();
    float acc[64];
    #pragma unroll
    for (int d = 0; d < 64; d++) acc[d] = 0.0f;
    for (int c = 0; c < 64; c++) {
        float x = lds[lane * 65 + c];
        const float* wr = W + c * 64;
        #pragma unroll
        for (int d = 0; d < 64; d++) acc[d] = fmaf(x, wr[d], acc[d]);
    }
    __syncthreads();
    #pragma unroll
    for (int d = 0; d < 64; d++) lds[lane * 65 + d] = acc[d];
    __syncthreads();
    for (int r = 0; r < nv; r++) outp[(size_t)(n0 + r) * ostride + lane] = lds[r * 65 + lane];
    __syncthreads();
}

// s_up = s @ Ws ; v_up[x] = v[x] @ Wv ; optionally zero agg buffers
__global__ void k_4mv(const float* __restrict__ ins, const float* __restrict__ inv,
                      const float* __restrict__ Ws, const float* __restrict__ Wv,
                      float* __restrict__ outs, float* __restrict__ outv,
                      float* __restrict__ agg0, float* __restrict__ agg1, int N) {
    __shared__ float lds[64 * 65];
    int lane = threadIdx.x;
    int n0 = blockIdx.x * 64;
    int nv = min(64, N - n0);
    tile_mv64(ins, 64, Ws, outs, 64, n0, nv, lds, lane);
    for (int x = 0; x < 3; x++)
        tile_mv64(inv + x * 64, 192, Wv, outv + x * 64, 192, n0, nv, lds, lane);
    if (agg0 != nullptr) {
        for (int r = 0; r < nv; r++) {
            size_t n = n0 + r;
            agg0[n * 64 + lane] = 0.0f;
            agg1[n * 192 + lane] = 0.0f;
            agg1[n * 192 + 64 + lane] = 0.0f;
            agg1[n * 192 + 128 + lane] = 0.0f;
        }
    }
}

// ---------------- edge kernel: radial MLP + messages + atomic scatter ----------------
__global__ void k_edge(const int* __restrict__ ei, const float* __restrict__ efT,
                       const float* __restrict__ Y1v, const float* __restrict__ s_up,
                       const float* __restrict__ v_up, const float* __restrict__ RW1,
                       const float* __restrict__ RW2, const float* __restrict__ RW3,
                       float* __restrict__ agg0, float* __restrict__ agg1, int E) {
    __shared__ float lh[64 * 64];   // h1 then h2, layout [c][lane]
    __shared__ float lw[64 * 41];   // per-chunk w, row stride 41 (pad)
    const int lane = threadIdx.x;
    const int e0 = blockIdx.x * 64;
    const int e = e0 + lane;
    const bool ve = (e < E);

    // ---- h1 = silu(ef @ RW1) ----
    float ef[8];
    #pragma unroll
    for (int k = 0; k < 8; k++) ef[k] = ve ? efT[k * (size_t)E + e] : 0.0f;
    float h[64];
    #pragma unroll
    for (int d = 0; d < 64; d++) h[d] = 0.0f;
    #pragma unroll
    for (int k = 0; k < 8; k++) {
        float x = ef[k];
        const float* wr = RW1 + k * 64;
        #pragma unroll
        for (int d = 0; d < 64; d++) h[d] = fmaf(x, wr[d], h[d]);
    }
    #pragma unroll
    for (int d = 0; d < 64; d++) lh[d * 64 + lane] = siluf(h[d]);
    __syncthreads();

    // ---- h2 = silu(h1 @ RW2) ----
    #pragma unroll
    for (int d = 0; d < 64; d++) h[d] = 0.0f;
    for (int c = 0; c < 64; c++) {
        float x = lh[c * 64 + lane];
        const float* wr = RW2 + c * 64;
        #pragma unroll
        for (int d = 0; d < 64; d++) h[d] = fmaf(x, wr[d], h[d]);
    }
    __syncthreads();
    #pragma unroll
    for (int d = 0; d < 64; d++) lh[d * 64 + lane] = siluf(h[d]);
    __syncthreads();

    const float inv32 = 1.0f / 32.0f;
    const float is3 = 0.5773502691896258f;   // 1/sqrt(3)
    const float is2 = 0.7071067811865476f;   // 1/sqrt(2)
    const int elb = lane >> 3;
    const int cj = lane & 7;

    // ---- w = h2 @ RW3, in chunks of 8 output channels; then messages ----
    for (int cc = 0; cc < 8; cc++) {
        float w[40];
        #pragma unroll
        for (int j = 0; j < 40; j++) w[j] = 0.0f;
        for (int c = 0; c < 64; c++) {
            float x = lh[c * 64 + lane];
            const float* wr = RW3 + c * 320 + cc * 8;
            #pragma unroll
            for (int q = 0; q < 5; q++) {
                #pragma unroll
                for (int j = 0; j < 8; j++)
                    w[q * 8 + j] = fmaf(x, wr[q * 64 + j], w[q * 8 + j]);
            }
        }
        __syncthreads();
        #pragma unroll
        for (int q = 0; q < 5; q++) {
            #pragma unroll
            for (int j = 0; j < 8; j++)
                lw[lane * 41 + q * 8 + j] = w[q * 8 + j];
        }
        __syncthreads();

        const int c = cc * 8 + cj;
        for (int t = 0; t < 8; t++) {
            int el = t * 8 + elb;
            int e2 = e0 + el;
            if (e2 < E) {
                int snd = ei[e2], rcv = ei[E + e2];
                float y0 = Y1v[e2 * 3 + 0], y1 = Y1v[e2 * 3 + 1], y2 = Y1v[e2 * 3 + 2];
                float w00  = lw[el * 41 + cj];
                float w110 = lw[el * 41 + 8 + cj];
                float w011 = lw[el * 41 + 16 + cj];
                float w101 = lw[el * 41 + 24 + cj];
                float w111 = lw[el * 41 + 32 + cj];
                size_t sb = (size_t)snd;
                float sj = s_up[sb * 64 + c];
                float v0 = v_up[sb * 192 + c];
                float v1 = v_up[sb * 192 + 64 + c];
                float v2 = v_up[sb * 192 + 128 + c];
                float dvy = v0 * y0 + v1 * y1 + v2 * y2;
                float m0 = (w00 * sj + w110 * dvy * is3) * inv32;
                float cx = v1 * y2 - v2 * y1;
                float cy = v2 * y0 - v0 * y2;
                float cz = v0 * y1 - v1 * y0;
                float m1x = (w011 * sj * y0 + w101 * v0 + w111 * cx * is2) * inv32;
                float m1y = (w011 * sj * y1 + w101 * v1 + w111 * cy * is2) * inv32;
                float m1z = (w011 * sj * y2 + w101 * v2 + w111 * cz * is2) * inv32;
                size_t rb = (size_t)rcv;
                atomicAdd(&agg0[rb * 64 + c], m0);
                atomicAdd(&agg1[rb * 192 + c], m1x);
                atomicAdd(&agg1[rb * 192 + 64 + c], m1y);
                atomicAdd(&agg1[rb * 192 + 128 + c], m1z);
            }
        }
        __syncthreads();
    }
}

// ---------------- species-dependent skip connections (wave = node) ----------------
__global__ void k_sc(const float* __restrict__ s, const float* __restrict__ v,
                     const int* __restrict__ species, const float* __restrict__ Wsc_s,
                     const float* __restrict__ Wsc_v, float* __restrict__ sc_s,
                     float* __restrict__ sc_v, int N) {
    int n = blockIdx.x;
    if (n >= N) return;
    int lane = threadIdx.x;
    int z = species[n];
    const float* Ws = Wsc_s + (size_t)z * 4096;
    const float* Wv = Wsc_v + (size_t)z * 4096;
    size_t nb = (size_t)n;
    float sreg = s[nb * 64 + lane];
    float acc = 0.0f;
    for (int c = 0; c < 64; c++)
        acc = fmaf(__shfl(sreg, c), Ws[c * 64 + lane], acc);
    sc_s[nb * 64 + lane] = acc;
    for (int x = 0; x < 3; x++) {
        float vreg = v[nb * 192 + x * 64 + lane];
        float av = 0.0f;
        for (int c = 0; c < 64; c++)
            av = fmaf(__shfl(vreg, c), Wv[c * 64 + lane], av);
        sc_v[nb * 192 + x * 64 + lane] = av;
    }
}

// ---------------- prod_s -> new s + output slot ----------------
__global__ void k_prod_s(const float* __restrict__ ms, const float* __restrict__ mv,
                         const float* __restrict__ P0l, const int* __restrict__ species,
                         const float* __restrict__ Wp, const float* __restrict__ sc_s,
                         float* __restrict__ s, float* __restrict__ out,
                         int N, int layer, int L) {
    __shared__ float lds[64 * 65];
    int lane = threadIdx.x;
    int n0 = blockIdx.x * 64;
    int nv = min(64, N - n0);
    for (int r = 0; r < nv; r++) {
        size_t n = n0 + r;
        int z = species[n];
        float msv = ms[n * 64 + lane];
        float a = mv[n * 192 + lane];
        float b = mv[n * 192 + 64 + lane];
        float cq = mv[n * 192 + 128 + lane];
        float mq = a * a + b * b + cq * cq;
        const float* p = P0l + ((size_t)z * 64 + lane) * 3;
        lds[r * 65 + lane] = p[0] * msv + p[1] * msv * msv + p[2] * mq;
    }
    __syncthreads();
    float acc[64];
    #pragma unroll
    for (int d = 0; d < 64; d++) acc[d] = 0.0f;
    for (int c = 0; c < 64; c++) {
        float x = lds[lane * 65 + c];
        const float* wr = Wp + c * 64;
        #pragma unroll
        for (int d = 0; d < 64; d++) acc[d] = fmaf(x, wr[d], acc[d]);
    }
    __syncthreads();
    #pragma unroll
    for (int d = 0; d < 64; d++) lds[lane * 65 + d] = acc[d];
    __syncthreads();
    for (int r = 0; r < nv; r++) {
        size_t n = n0 + r;
        float val = lds[r * 65 + lane] + sc_s[n * 64 + lane];
        s[n * 64 + lane] = val;
        out[n * (size_t)(L * 64) + layer * 64 + lane] = val;
    }
}

// ---------------- prod_v -> new v ----------------
__global__ void k_prod_v(const float* __restrict__ ms, const float* __restrict__ mv,
                         const float* __restrict__ P1l, const int* __restrict__ species,
                         const float* __restrict__ Wp, const float* __restrict__ sc_v,
                         float* __restrict__ v, int N) {
    __shared__ float lds[64 * 65];
    int lane = threadIdx.x;
    int n0 = blockIdx.x * 64;
    int nv = min(64, N - n0);
    for (int x = 0; x < 3; x++) {
        for (int r = 0; r < nv; r++) {
            size_t n = n0 + r;
            int z = species[n];
            float msv = ms[n * 64 + lane];
            float mvv = mv[n * 192 + x * 64 + lane];
            const float* q = P1l + ((size_t)z * 64 + lane) * 2;
            lds[r * 65 + lane] = (q[0] + q[1] * msv) * mvv;
        }
        __syncthreads();
        float acc[64];
        #pragma unroll
        for (int d = 0; d < 64; d++) acc[d] = 0.0f;
        for (int c = 0; c < 64; c++) {
            float xx = lds[lane * 65 + c];
            const float* wr = Wp + c * 64;
            #pragma unroll
            for (int d = 0; d < 64; d++) acc[d] = fmaf(xx, wr[d], acc[d]);
        }
        __syncthreads();
        #pragma unroll
        for (int d = 0; d < 64; d++) lds[lane * 65 + d] = acc[d];
        __syncthreads();
        for (int r = 0; r < nv; r++) {
            size_t n = n0 + r;
            v[n * 192 + x * 64 + lane] = lds[r * 65 + lane] + sc_v[n * 192 + x * 64 + lane];
        }
        __syncthreads();
    }
}

extern "C" void kernel_launch(void* const* d_in, const int* in_sizes, int n_in,
                              void* d_out, int out_size, void* d_ws, size_t ws_size,
                              hipStream_t stream) {
    const float* node_attrs = (const float*)d_in[0];
    const float* atom_pos   = (const float*)d_in[1];
    const float* shifts     = (const float*)d_in[2];
    const float* W_embed    = (const float*)d_in[3];
    const float* Wup_s      = (const float*)d_in[4];
    const float* Wup_v      = (const float*)d_in[5];
    const float* RW1        = (const float*)d_in[6];
    const float* RW2        = (const float*)d_in[7];
    const float* RW3        = (const float*)d_in[8];
    const float* Wout_s     = (const float*)d_in[9];
    const float* Wout_v     = (const float*)d_in[10];
    const float* Wsc_s      = (const float*)d_in[11];
    const float* Wsc_v      = (const float*)d_in[12];
    const float* P0         = (const float*)d_in[13];
    const float* P1         = (const float*)d_in[14];
    const float* Wprod_s    = (const float*)d_in[15];
    const float* Wprod_v    = (const float*)d_in[16];
    const int*   ei         = (const int*)d_in[17];

    const int N = in_sizes[0] / 10;
    const int E = in_sizes[17] / 2;
    const int L = in_sizes[4] / 4096;
    float* out = (float*)d_out;

    char* wsb = (char*)d_ws;
    size_t off = 0;
    int* species = (int*)wsb;
    off = ((size_t)N * 4 + 255) / 256 * 256;
    auto alloc = [&](size_t nfl) {
        float* p = (float*)(wsb + off);
        off += nfl * sizeof(float);
        return p;
    };
    float* s    = alloc((size_t)N * 64);
    float* v    = alloc((size_t)N * 192);
    float* s_up = alloc((size_t)N * 64);   // reused as ms
    float* v_up = alloc((size_t)N * 192);  // reused as mv
    float* agg0 = alloc((size_t)N * 64);
    float* agg1 = alloc((size_t)N * 192);
    float* sc_s = alloc((size_t)N * 64);
    float* sc_v = alloc((size_t)N * 192);
    float* Y1v  = alloc((size_t)E * 3);
    float* efT  = alloc((size_t)E * 8);
    (void)ws_size; (void)n_in; (void)out_size;

    const int NT = (N + 63) / 64;
    const int ET = (E + 63) / 64;

    k_init<<<NT, 64, 0, stream>>>(node_attrs, W_embed, species, s, v, N);
    k_geom<<<ET, 64, 0, stream>>>(ei, atom_pos, shifts, Y1v, efT, E);

    for (int i = 0; i < L; i++) {
        k_4mv<<<NT, 64, 0, stream>>>(s, v, Wup_s + (size_t)i * 4096, Wup_v + (size_t)i * 4096,
                                     s_up, v_up, agg0, agg1, N);
        k_edge<<<ET, 64, 0, stream>>>(ei, efT, Y1v, s_up, v_up,
                                      RW1 + (size_t)i * 512, RW2 + (size_t)i * 4096,
                                      RW3 + (size_t)i * 20480, agg0, agg1, E);
        k_sc<<<N, 64, 0, stream>>>(s, v, species, Wsc_s + (size_t)i * 40960,
                                   Wsc_v + (size_t)i * 40960, sc_s, sc_v, N);
        // ms -> s_up, mv -> v_up (s_up/v_up dead after k_edge)
        k_4mv<<<NT, 64, 0, stream>>>(agg0, agg1, Wout_s + (size_t)i * 4096,
                                     Wout_v + (size_t)i * 4096, s_up, v_up,
                                     nullptr, nullptr, N);
        k_prod_s<<<NT, 64, 0, stream>>>(s_up, v_up, P0 + (size_t)i * 1920, species,
                                        Wprod_s + (size_t)i * 4096, sc_s, s, out, N, i, L);
        k_prod_v<<<NT, 64, 0, stream>>>(s_up, v_up, P1 + (size_t)i * 1280, species,
                                        Wprod_v + (size_t)i * 4096, sc_v, v, N);
    }
}